// Round 1
// baseline (1853.135 us; speedup 1.0000x reference)
//
#include <hip/hip_runtime.h>

// L2BoundedLTICell on MI355X (gfx950)
// B=16, T=4096, H=N=P=512, K_raw 1024x1024.
// out = [output (16x4096x512) | states (16x4097x512)] fp32.

typedef unsigned short u16;
typedef __bf16 bf16x8 __attribute__((ext_vector_type(8)));
typedef u16    u16x8  __attribute__((ext_vector_type(8)));
typedef float  f32x4  __attribute__((ext_vector_type(4)));

#define DIVBIG 0x40000000u

static_assert(sizeof(long) == 8, "need 64-bit long");

__device__ inline u16 f2bf(float f) {
    union { float f; unsigned u; } x; x.f = f;
    unsigned r = x.u + 0x7FFFu + ((x.u >> 16) & 1u);
    return (u16)(r >> 16);
}

// ---------------------------------------------------------------------------
// bf16 MFMA GEMM.  Out[r][c] = beta*Init[r][c] + sum_k Asrc[r][k]*Bpanel[k][c]
//  - A is FP32, read per-lane (converted to bf16 in-register).
//  - B is bf16 in panel layout: element (k,n) at ((k>>3)*ldbN + n)*8 + (k&7).
//  - Row r of A1 maps to A1 + (r/a1Div)*a1BS + (r%a1Div)*a1RS (floats).
//    k-iters [0,K1it) read A1 (k offset kk*32), [K1it,Kit) read A2.
//  - shiftA shifts A1's row index (scan); rows with (r%predMod)<predLow get
//    a zero A1 contribution (scan masking).
// Wave layout: 4 waves split N (128 cols each); MF m-fragments of 16 rows.
// ---------------------------------------------------------------------------
struct GemmArgs {
    const float* A1; long a1BS, a1RS; unsigned a1Div; int shiftA;
    const float* A2; long a2BS, a2RS; unsigned a2Div;
    const u16*   Bp; long ldbN, colOff;
    const float* initP; long iBS, iRS; unsigned iDiv; float beta;
    float* Out; long oBS, oRS; unsigned oDiv;
    int Kit, K1it;
    unsigned predMod; int predLow;
    float* sumsq;
};

template<int MF>
__global__ __launch_bounds__(256) void gemm_bf16(GemmArgs g) {
    const int lane = threadIdx.x & 63;
    const int wv   = threadIdx.x >> 6;
    const int kg   = lane >> 4;
    const int l15  = lane & 15;
    const unsigned row0 = blockIdx.x * (16 * MF);
    const long cb = (long)blockIdx.y * 512 + wv * 128;

    const float* ap1[MF];
    const float* ap2[MF];
    bool pr[MF];
#pragma unroll
    for (int mf = 0; mf < MF; ++mf) {
        unsigned r = row0 + mf * 16 + l15;
        pr[mf] = (g.predLow == 0) || ((r % g.predMod) >= (unsigned)g.predLow);
        long ra = (long)r - g.shiftA; if (ra < 0) ra = 0;
        unsigned ru = (unsigned)ra;
        ap1[mf] = g.A1 + (long)(ru / g.a1Div) * g.a1BS + (long)(ru % g.a1Div) * g.a1RS + kg * 8;
        ap2[mf] = nullptr;
        if (g.A2)
            ap2[mf] = g.A2 + (long)(r / g.a2Div) * g.a2BS + (long)(r % g.a2Div) * g.a2RS + kg * 8;
    }

    f32x4 acc[MF][8];
#pragma unroll
    for (int mf = 0; mf < MF; ++mf)
#pragma unroll
        for (int nf = 0; nf < 8; ++nf)
            acc[mf][nf] = (f32x4){0.f, 0.f, 0.f, 0.f};

    if (g.initP) {
#pragma unroll
        for (int mf = 0; mf < MF; ++mf)
#pragma unroll
            for (int q = 0; q < 4; ++q) {
                unsigned r = row0 + mf * 16 + kg * 4 + q;
                const float* ip = g.initP + (long)(r / g.iDiv) * g.iBS
                                + (long)(r % g.iDiv) * g.iRS + cb + l15;
#pragma unroll
                for (int nf = 0; nf < 8; ++nf)
                    acc[mf][nf][q] = g.beta * ip[nf * 16];
            }
    }

    const u16* bp = g.Bp + ((long)kg * g.ldbN + g.colOff + cb + l15) * 8;
    const long bstep = g.ldbN * 32;

    for (int kk = 0; kk < g.K1it; ++kk) {
        bf16x8 af[MF];
#pragma unroll
        for (int mf = 0; mf < MF; ++mf) {
            float4 v0 = *(const float4*)(ap1[mf]);
            float4 v1 = *(const float4*)(ap1[mf] + 4);
            ap1[mf] += 32;
            bf16x8 a;
            a[0] = (__bf16)v0.x; a[1] = (__bf16)v0.y; a[2] = (__bf16)v0.z; a[3] = (__bf16)v0.w;
            a[4] = (__bf16)v1.x; a[5] = (__bf16)v1.y; a[6] = (__bf16)v1.z; a[7] = (__bf16)v1.w;
            if (!pr[mf]) { u16x8 z = {0,0,0,0,0,0,0,0}; a = __builtin_bit_cast(bf16x8, z); }
            af[mf] = a;
        }
#pragma unroll
        for (int nf = 0; nf < 8; ++nf) {
            u16x8 braw = *(const u16x8*)(bp + (long)nf * 128);
            bf16x8 bb = __builtin_bit_cast(bf16x8, braw);
#pragma unroll
            for (int mf = 0; mf < MF; ++mf)
                acc[mf][nf] = __builtin_amdgcn_mfma_f32_16x16x32_bf16(af[mf], bb, acc[mf][nf], 0, 0, 0);
        }
        bp += bstep;
    }
    if (g.A2) {
        const int K2 = g.Kit - g.K1it;
        for (int kk = 0; kk < K2; ++kk) {
            bf16x8 af[MF];
#pragma unroll
            for (int mf = 0; mf < MF; ++mf) {
                float4 v0 = *(const float4*)(ap2[mf]);
                float4 v1 = *(const float4*)(ap2[mf] + 4);
                ap2[mf] += 32;
                bf16x8 a;
                a[0] = (__bf16)v0.x; a[1] = (__bf16)v0.y; a[2] = (__bf16)v0.z; a[3] = (__bf16)v0.w;
                a[4] = (__bf16)v1.x; a[5] = (__bf16)v1.y; a[6] = (__bf16)v1.z; a[7] = (__bf16)v1.w;
                af[mf] = a;
            }
#pragma unroll
            for (int nf = 0; nf < 8; ++nf) {
                u16x8 braw = *(const u16x8*)(bp + (long)nf * 128);
                bf16x8 bb = __builtin_bit_cast(bf16x8, braw);
#pragma unroll
                for (int mf = 0; mf < MF; ++mf)
                    acc[mf][nf] = __builtin_amdgcn_mfma_f32_16x16x32_bf16(af[mf], bb, acc[mf][nf], 0, 0, 0);
            }
            bp += bstep;
        }
    }

    float ss = 0.f;
#pragma unroll
    for (int mf = 0; mf < MF; ++mf)
#pragma unroll
        for (int q = 0; q < 4; ++q) {
            unsigned r = row0 + mf * 16 + kg * 4 + q;
            float* op = g.Out + (long)(r / g.oDiv) * g.oBS
                      + (long)(r % g.oDiv) * g.oRS + cb + l15;
#pragma unroll
            for (int nf = 0; nf < 8; ++nf) {
                float v = acc[mf][nf][q];
                op[nf * 16] = v;
                ss += v * v;
            }
        }
    if (g.sumsq) {
#pragma unroll
        for (int off = 32; off; off >>= 1) ss += __shfl_down(ss, off);
        if (lane == 0) atomicAdd(g.sumsq, ss);
    }
}

// ---------------------------------------------------------------------------
// fp32 GEMM 512x512x512 (Newton polish only): O = alpha*A@B + beta*I
// ---------------------------------------------------------------------------
__global__ __launch_bounds__(256) void gemm_f32_512(const float* A, const float* B,
                                                    const float* I, float* O,
                                                    float alpha, float beta) {
    __shared__ float As[16][68];
    __shared__ float Bs[16][68];
    const int tx = threadIdx.x & 15, ty = threadIdx.x >> 4;
    const int bm = blockIdx.x * 64, bn = blockIdx.y * 64;
    float acc[4][4] = {};
    for (int k0 = 0; k0 < 512; k0 += 16) {
        for (int t = threadIdx.x; t < 1024; t += 256) {
            int r = t >> 4, c = t & 15;
            As[c][r] = A[(long)(bm + r) * 512 + k0 + c];
            int r2 = t >> 6, c2 = t & 63;
            Bs[r2][c2] = B[(long)(k0 + r2) * 512 + bn + c2];
        }
        __syncthreads();
#pragma unroll
        for (int k = 0; k < 16; ++k)
#pragma unroll
            for (int i = 0; i < 4; ++i)
#pragma unroll
                for (int j = 0; j < 4; ++j)
                    acc[i][j] += As[k][ty * 4 + i] * Bs[k][tx * 4 + j];
        __syncthreads();
    }
#pragma unroll
    for (int i = 0; i < 4; ++i)
#pragma unroll
        for (int j = 0; j < 4; ++j) {
            long o = (long)(bm + ty * 4 + i) * 512 + bn + tx * 4 + j;
            float v = alpha * acc[i][j];
            if (I) v += beta * I[o];
            O[o] = v;
        }
}

// ---------------------------------------------------------------------------
// small utility kernels
// ---------------------------------------------------------------------------
// panel(k,n) = src[k][n]*scale  (scale optionally rsqrt of sumsq slot; lnacc update)
__global__ __launch_bounds__(256) void k_cast_panel(const float* src, long srcLd, int R, int C,
                                                    u16* panel, long pLd, float* dstF,
                                                    float cScale, float* slots, int ssIdx, float lnW) {
    float scale = cScale;
    if (ssIdx >= 0) scale *= rsqrtf(fmaxf(slots[ssIdx], 1e-30f));
    if (lnW != 0.f && blockIdx.x == 0 && threadIdx.x == 0)
        slots[16] += lnW * 0.5f * logf(fmaxf(slots[ssIdx], 1e-30f));
    long total = (long)R * C;
    for (long idx = (long)blockIdx.x * 256 + threadIdx.x; idx < total; idx += (long)gridDim.x * 256) {
        long k = idx / C, n = idx % C;
        float v = src[k * srcLd + n] * scale;
        panel[((k >> 3) * pLd + n) * 8 + (k & 7)] = f2bf(v);
        if (dstF) dstF[k * (long)C + n] = v;
    }
}

// panel(k=j,n=i) = src[i][j]*scale  (transpose); optional fp32 transpose out
__global__ __launch_bounds__(256) void k_transpose_cast(const float* src, long srcLd, int R, int C,
                                                        u16* panel, long pLd, float* dstFT,
                                                        const float* slots, int sIdx) {
    float scale = (sIdx >= 0) ? slots[sIdx] : 1.0f;
    long total = (long)R * C;
    for (long idx = (long)blockIdx.x * 256 + threadIdx.x; idx < total; idx += (long)gridDim.x * 256) {
        long i = idx / C, j = idx % C;
        float v = src[i * srcLd + j] * scale;
        if (panel) panel[((j >> 3) * pLd + i) * 8 + (j & 7)] = f2bf(v);
        if (dstFT) dstFT[j * (long)R + i] = v;
    }
}

__global__ __launch_bounds__(256) void k_x1(const float* S, float* Xf, u16* Xp) {
    for (long idx = (long)blockIdx.x * 256 + threadIdx.x; idx < 262144; idx += (long)gridDim.x * 256) {
        int i = (int)(idx >> 9), j = (int)(idx & 511);
        float v = ((i == j) ? 2.0f : 0.0f) - S[idx];
        Xf[idx] = v;
        Xp[(((long)(i >> 3)) * 512 + j) * 8 + (i & 7)] = f2bf(v);
    }
}

__global__ void k_fin(float* slots, const float* lg) {
    float sigma = expf(0.5f * slots[16]);
    sigma = fmaxf(sigma, 1e-5f);
    float s = sigma + 0.002f;
    float g = expf(lg[0]);
    slots[32] = 1.0f / s;   // s_inv
    slots[33] = g / s;      // gamma * s_inv
}

__global__ __launch_bounds__(256) void k_zrows(float* Z0, const float* state) {
    int idx = blockIdx.x * 256 + threadIdx.x;
    if (idx < 8192) {
        int b = idx >> 9, n = idx & 511;
        Z0[(long)b * 262144 + n] = state[idx];   // row r=b*512 (chunk 0)
    }
}

__global__ __launch_bounds__(256) void k_seed(float* states, const float* W, const float* state) {
    long total = 8192L * 512;
    for (long idx = (long)blockIdx.x * 256 + threadIdx.x; idx < total; idx += (long)gridDim.x * 256) {
        long r = idx >> 9; int n = (int)(idx & 511);
        long b = r >> 9, c = r & 511;
        float v = (c == 0) ? state[(b << 9) + n] : W[((r - 1) << 9) + n];
        states[b * 2097664 + c * 4096 + n] = v;  // states[b][c*8][n]
    }
}

// ---------------------------------------------------------------------------
extern "C" void kernel_launch(void* const* d_in, const int* in_sizes, int n_in,
                              void* d_out, int out_size, void* d_ws, size_t ws_size,
                              hipStream_t stream) {
    (void)in_sizes; (void)n_in; (void)out_size; (void)ws_size;

    const float* u     = (const float*)d_in[0];   // 16 x 4096 x 512
    const float* state = (const float*)d_in[1];   // 16 x 512
    const float* S     = (const float*)d_in[2];   // 512 x 512
    const float* K     = (const float*)d_in[3];   // 1024 x 1024
    const float* lg    = (const float*)d_in[4];   // scalar

    float* out    = (float*)d_out;                // 16 x 4096 x 512
    float* states = out + 33554432L;              // 16 x 4097 x 512

    // Z ping-pong buffers live in the (last-written) output region of d_out.
    float* Z0 = out;                               // 8192 x 512
    float* Z1 = out + 8192L * 512;

    // workspace bump allocator
    char* w = (char*)d_ws;
    auto alloc = [&](size_t n) { void* p = w; w += (n + 255) & ~(size_t)255; return p; };
    float* slots = (float*)alloc(256);             // [0..8] sumsq, [16] lnacc, [32..33] scales
    float* KTf = (float*)alloc(1024L * 1024 * 4);
    u16*   Kp  = (u16*)  alloc(1024L * 1024 * 2);
    float* Gb  = (float*)alloc(1024L * 1024 * 4);
    float* Mf  = (float*)alloc(1024L * 1024 * 4);
    u16*   Mp  = (u16*)  alloc(1024L * 1024 * 2);
    u16*   Sp  = (u16*)  alloc(512L * 512 * 2);
    float* Xaf = (float*)alloc(512L * 512 * 4);
    u16*   Xap = (u16*)  alloc(512L * 512 * 2);
    float* Xbf = (float*)alloc(512L * 512 * 4);
    u16*   Xbp = (u16*)  alloc(512L * 512 * 2);
    float* Pf  = (float*)alloc(512L * 512 * 4);
    u16*   Pp  = (u16*)  alloc(512L * 512 * 2);
    float* Xs  = (float*)alloc(512L * 512 * 4);
    float* T1f = (float*)alloc(512L * 512 * 4);
    u16*   T1p = (u16*)  alloc(512L * 512 * 2);
    float* Af  = (float*)alloc(512L * 512 * 4);
    float* Bmf = (float*)alloc(512L * 512 * 4);
    float* Cmf = (float*)alloc(512L * 512 * 4);
    float* ATf = (float*)alloc(512L * 512 * 4);
    float* Wf1 = (float*)alloc(512L * 512 * 4);
    float* Wf2 = (float*)alloc(512L * 512 * 4);
    u16*   Q1  = (u16*)  alloc(512L * 512 * 2);
    u16*   Q2  = (u16*)  alloc(512L * 512 * 2);
    u16*   P8p = (u16*)  alloc(512L * 512 * 2);
    u16*   P16p= (u16*)  alloc(512L * 512 * 2);
    u16*   ABT = (u16*)  alloc(1024L * 512 * 2);  // [AT;BT] panels
    u16*   CDT = (u16*)  alloc(1024L * 512 * 2);  // [CT;DT] panels

    auto mkargs = [&]() {
        GemmArgs a = {};
        a.a1Div = DIVBIG; a.a2Div = DIVBIG; a.iDiv = DIVBIG; a.oDiv = DIVBIG;
        a.predMod = 512; a.predLow = 0; a.beta = 1.f; a.shiftA = 0;
        return a;
    };
    auto launch_gemm = [&](int MF, int M, int N, const GemmArgs& a) {
        dim3 gr(M / (16 * MF), N / 512);
        if (MF == 2) gemm_bf16<2><<<gr, 256, 0, stream>>>(a);
        else         gemm_bf16<1><<<gr, 256, 0, stream>>>(a);
    };

    hipMemsetAsync(slots, 0, 256, stream);
    hipMemsetAsync(Z0, 0, 8192L * 512 * 4, stream);

    // ---- sigma = ||K||_2 via normalized repeated squaring of K^T K --------
    k_transpose_cast<<<4096, 256, 0, stream>>>(K, 1024, 1024, 1024, nullptr, 0, KTf, nullptr, -1);
    k_cast_panel<<<4096, 256, 0, stream>>>(K, 1024, 1024, 1024, Kp, 1024, nullptr, 1.f, slots, -1, 0.f);
    {   // G0 = KT @ K (bf16, frob epilogue -> slots[0])
        GemmArgs a = mkargs();
        a.A1 = KTf; a.a1RS = 1024;
        a.Bp = Kp; a.ldbN = 1024; a.colOff = 0;
        a.Out = Gb; a.oRS = 1024;
        a.Kit = 32; a.K1it = 32; a.sumsq = slots + 0;
        launch_gemm(1, 1024, 1024, a);
    }
    k_cast_panel<<<4096, 256, 0, stream>>>(Gb, 1024, 1024, 1024, Mp, 1024, Mf, 1.f, slots, 0, 1.0f);
    for (int i = 1; i <= 8; ++i) {
        GemmArgs a = mkargs();
        a.A1 = Mf; a.a1RS = 1024;
        a.Bp = Mp; a.ldbN = 1024;
        a.Out = Gb; a.oRS = 1024;
        a.Kit = 32; a.K1it = 32; a.sumsq = slots + i;
        launch_gemm(1, 1024, 1024, a);
        k_cast_panel<<<4096, 256, 0, stream>>>(Gb, 1024, 1024, 1024, Mp, 1024, Mf,
                                               1.f, slots, i, 1.0f / (float)(1 << i));
    }
    k_fin<<<1, 1, 0, stream>>>(slots, lg);

    // ---- Sinv via Newton (4 bf16 iters + 1 fp32 polish) --------------------
    k_cast_panel<<<1024, 256, 0, stream>>>(S, 512, 512, 512, Sp, 512, nullptr, 1.f, slots, -1, 0.f);
    k_x1<<<1024, 256, 0, stream>>>(S, Xaf, Xap);   // X1 = 2I - S
    float* curF = Xaf; u16* curP = Xap; float* nxtF = Xbf; u16* nxtP = Xbp;
    for (int it = 0; it < 4; ++it) {
        GemmArgs a = mkargs();           // P = S @ X
        a.A1 = S; a.a1RS = 512;
        a.Bp = curP; a.ldbN = 512;
        a.Out = Pf; a.oRS = 512;
        a.Kit = 16; a.K1it = 16;
        launch_gemm(1, 512, 512, a);
        k_cast_panel<<<1024, 256, 0, stream>>>(Pf, 512, 512, 512, Pp, 512, nullptr, -1.f, slots, -1, 0.f);
        GemmArgs b = mkargs();           // Xnew = 2X + X @ (-P)
        b.A1 = curF; b.a1RS = 512;
        b.Bp = Pp; b.ldbN = 512;
        b.initP = curF; b.iRS = 512; b.beta = 2.f;
        b.Out = nxtF; b.oRS = 512;
        b.Kit = 16; b.K1it = 16;
        launch_gemm(1, 512, 512, b);
        k_cast_panel<<<1024, 256, 0, stream>>>(nxtF, 512, 512, 512, nxtP, 512, nullptr, 1.f, slots, -1, 0.f);
        float* tf = curF; curF = nxtF; nxtF = tf;
        u16*   tp = curP; curP = nxtP; nxtP = tp;
    }
    gemm_f32_512<<<dim3(8, 8), 256, 0, stream>>>(S, curF, nullptr, Pf, 1.f, 0.f);
    gemm_f32_512<<<dim3(8, 8), 256, 0, stream>>>(curF, Pf, curF, Xs, -1.f, 2.f);

    // ---- A,B,C,D prep ------------------------------------------------------
    {   // T1 = K11 @ S
        GemmArgs a = mkargs();
        a.A1 = K; a.a1RS = 1024;
        a.Bp = Sp; a.ldbN = 512;
        a.Out = T1f; a.oRS = 512; a.Kit = 16; a.K1it = 16;
        launch_gemm(1, 512, 512, a);
    }
    k_cast_panel<<<1024, 256, 0, stream>>>(T1f, 512, 512, 512, T1p, 512, nullptr, 1.f, slots, -1, 0.f);
    {   // Af = Sinv @ T1
        GemmArgs a = mkargs();
        a.A1 = Xs; a.a1RS = 512; a.Bp = T1p; a.ldbN = 512;
        a.Out = Af; a.oRS = 512; a.Kit = 16; a.K1it = 16;
        launch_gemm(1, 512, 512, a);
    }
    {   // Bmf = Sinv @ K12
        GemmArgs a = mkargs();
        a.A1 = Xs; a.a1RS = 512; a.Bp = Kp; a.ldbN = 1024; a.colOff = 512;
        a.Out = Bmf; a.oRS = 512; a.Kit = 16; a.K1it = 16;
        launch_gemm(1, 512, 512, a);
    }
    {   // Cmf = K21 @ S
        GemmArgs a = mkargs();
        a.A1 = K + 512L * 1024; a.a1RS = 1024; a.Bp = Sp; a.ldbN = 512;
        a.Out = Cmf; a.oRS = 512; a.Kit = 16; a.K1it = 16;
        launch_gemm(1, 512, 512, a);
    }
    // ABT = [A^T * s_inv ; B^T * g*s_inv], CDT = [C^T * s_inv ; D^T]
    k_transpose_cast<<<1024, 256, 0, stream>>>(Af, 512, 512, 512, ABT, 512, ATf, slots, 32);
    k_transpose_cast<<<1024, 256, 0, stream>>>(Bmf, 512, 512, 512, ABT + 262144, 512, nullptr, slots, 33);
    k_transpose_cast<<<1024, 256, 0, stream>>>(Cmf, 512, 512, 512, CDT, 512, nullptr, slots, 32);
    k_transpose_cast<<<1024, 256, 0, stream>>>(K + 512L * 1024 + 512, 1024, 512, 512,
                                               CDT + 262144, 512, nullptr, slots, 33);
    // powers of A^T: AT2, AT4, AT8 (panel P8p), AT16 (panel P16p)
    {
        GemmArgs a = mkargs();
        a.A1 = ATf; a.a1RS = 512; a.Bp = ABT; a.ldbN = 512;
        a.Out = Wf1; a.oRS = 512; a.Kit = 16; a.K1it = 16;
        launch_gemm(1, 512, 512, a);
        k_cast_panel<<<1024, 256, 0, stream>>>(Wf1, 512, 512, 512, Q1, 512, nullptr, 1.f, slots, -1, 0.f);
        a.A1 = Wf1; a.Bp = Q1; a.Out = Wf2;
        launch_gemm(1, 512, 512, a);
        k_cast_panel<<<1024, 256, 0, stream>>>(Wf2, 512, 512, 512, Q2, 512, nullptr, 1.f, slots, -1, 0.f);
        a.A1 = Wf2; a.Bp = Q2; a.Out = Wf1;
        launch_gemm(1, 512, 512, a);
        k_cast_panel<<<1024, 256, 0, stream>>>(Wf1, 512, 512, 512, P8p, 512, nullptr, 1.f, slots, -1, 0.f);
        a.A1 = Wf1; a.Bp = P8p; a.Out = Wf2;
        launch_gemm(1, 512, 512, a);
        k_cast_panel<<<1024, 256, 0, stream>>>(Wf2, 512, 512, 512, P16p, 512, nullptr, 1.f, slots, -1, 0.f);
    }

    // ---- core: chunked scan, L=8, M=512 chunks, R = 16*512 = 8192 rows -----
    k_zrows<<<32, 256, 0, stream>>>(Z0, state);

    // Phase A: local recurrences from z0 (= state for chunk 0, else 0)
    for (int j = 1; j <= 8; ++j) {
        GemmArgs a = mkargs();
        a.A1 = (j & 1) ? Z0 : Z1; a.a1RS = 512;
        a.A2 = u + (long)(j - 1) * 512; a.a2Div = 512; a.a2BS = 2097152; a.a2RS = 4096;
        a.Bp = ABT; a.ldbN = 512;
        a.Out = (j & 1) ? Z1 : Z0; a.oRS = 512;
        a.Kit = 32; a.K1it = 16;
        launch_gemm(2, 8192, 512, a);
    }
    // Kogge-Stone carries (2 rounds suffice: ||A^32|| < 1e-4)
    {
        GemmArgs a = mkargs();
        a.A1 = Z0; a.a1RS = 512; a.shiftA = 1; a.predMod = 512; a.predLow = 1;
        a.Bp = P8p; a.ldbN = 512;
        a.initP = Z0; a.iRS = 512; a.beta = 1.f;
        a.Out = Z1; a.oRS = 512;
        a.Kit = 16; a.K1it = 16;
        launch_gemm(2, 8192, 512, a);
        a = mkargs();
        a.A1 = Z1; a.a1RS = 512; a.shiftA = 2; a.predMod = 512; a.predLow = 2;
        a.Bp = P16p; a.ldbN = 512;
        a.initP = Z1; a.iRS = 512; a.beta = 1.f;
        a.Out = Z0; a.oRS = 512;
        a.Kit = 16; a.K1it = 16;
        launch_gemm(2, 8192, 512, a);
    }
    // seed chunk boundary states (and states[:,0,:] = state)
    k_seed<<<8192, 256, 0, stream>>>(states, Z0, state);

    // Phase C: re-run recurrence with correct carries, writing states
    for (int j = 1; j <= 8; ++j) {
        GemmArgs a = mkargs();
        a.A1 = states + (long)(j - 1) * 512; a.a1Div = 512; a.a1BS = 2097664; a.a1RS = 4096;
        a.A2 = u + (long)(j - 1) * 512; a.a2Div = 512; a.a2BS = 2097152; a.a2RS = 4096;
        a.Bp = ABT; a.ldbN = 512;
        a.Out = states + (long)j * 512; a.oDiv = 512; a.oBS = 2097664; a.oRS = 4096;
        a.Kit = 32; a.K1it = 16;
        launch_gemm(2, 8192, 512, a);
    }

    // ---- output = pre_states @ C^T + u @ D^T  (single K=1024 GEMM) ---------
    {
        GemmArgs a = mkargs();
        a.A1 = states; a.a1Div = 4096; a.a1BS = 2097664; a.a1RS = 512;
        a.A2 = u;      a.a2Div = 4096; a.a2BS = 2097152; a.a2RS = 512;
        a.Bp = CDT; a.ldbN = 512;
        a.Out = out; a.oDiv = 4096; a.oBS = 2097152; a.oRS = 512;
        a.Kit = 32; a.K1it = 16;
        launch_gemm(2, 65536, 512, a);
    }
}